// Round 3
// baseline (658.021 us; speedup 1.0000x reference)
//
#include <hip/hip_runtime.h>

#define MID 3
#define NVEC 32
#define ROW_F 96   // MID*NVEC
#define NREP 8     // histogram replicas (one per XCD)

// ---------------------------------------------------------------------------
// Device-built CSR over 2N segments: seg n   = edges with dst==n  (side 1)
//                                    seg N+n = edges with src==n  (side 2)
// Atomic traffic is privatized per-XCD: block b uses histogram replica b&7,
// so counter cachelines never migrate across XCDs. reduce_kernel converts the
// replicas in-place to per-replica exclusive prefixes and emits total counts;
// scatter composes off[bin] + rep_prefix[rep][bin] + rank with NO atomics.
// Random 4B stores (list, ranks) are non-temporal to avoid L2 line-ownership
// ping-pong across XCDs.
// ws layout (ints): hrep[8*2N] | tot[2N] | off[2N] | rank1[E] | rank2[E] |
//                   list[2E] | bsum[256]   (~17 MB)
// ---------------------------------------------------------------------------

__global__ __launch_bounds__(256) void hist_kernel(
    const int* __restrict__ dst, const int* __restrict__ src,
    int* __restrict__ hrep, int* __restrict__ rank1, int* __restrict__ rank2,
    int E, int N, int nseg)
{
    int t = blockIdx.x * blockDim.x + threadIdx.x;
    if (t >= E) return;
    int* h = hrep + (size_t)(blockIdx.x & (NREP - 1)) * nseg;
    int r1 = atomicAdd(&h[dst[t]], 1);
    int r2 = atomicAdd(&h[N + src[t]], 1);
    __builtin_nontemporal_store(r1, &rank1[t]);
    __builtin_nontemporal_store(r2, &rank2[t]);
}

// replicas -> in-place exclusive prefix over r; totals out. 4 bins/thread.
__global__ __launch_bounds__(256) void reduce_kernel(
    int* __restrict__ hrep, int* __restrict__ tot, int nseg)
{
    int i4 = (blockIdx.x * blockDim.x + threadIdx.x) * 4;
    if (i4 >= nseg) return;
    if (i4 + 3 < nseg) {
        int4 s = make_int4(0, 0, 0, 0);
        #pragma unroll
        for (int r = 0; r < NREP; ++r) {
            int* p = hrep + (size_t)r * nseg + i4;
            int4 v = *(const int4*)p;
            *(int4*)p = s;                 // exclusive prefix over replicas
            s.x += v.x; s.y += v.y; s.z += v.z; s.w += v.w;
        }
        *(int4*)(tot + i4) = s;
    } else {
        for (int k = 0; k < 4 && i4 + k < nseg; ++k) {
            int s = 0;
            for (int r = 0; r < NREP; ++r) {
                int* p = hrep + (size_t)r * nseg + i4 + k;
                int v = *p; *p = s; s += v;
            }
            tot[i4 + k] = s;
        }
    }
}

// --- parallel scan: A) per-block sums, B) scan of block sums, C) local scan+add
#define SCAN_TPB 256
#define SCAN_EPB 1024   // elems per block (4 per thread, int4)

__global__ __launch_bounds__(SCAN_TPB) void scanA_kernel(
    const int* __restrict__ cnt, int* __restrict__ bsum, int n)
{
    __shared__ int sdata[SCAN_TPB];
    int b = blockIdx.x, t = threadIdx.x;
    int i4 = b * SCAN_EPB + t * 4;
    int s = 0;
    if (i4 + 3 < n) {
        int4 v = *(const int4*)(cnt + i4);
        s = v.x + v.y + v.z + v.w;
    } else {
        for (int k = 0; k < 4; ++k) if (i4 + k < n) s += cnt[i4 + k];
    }
    sdata[t] = s;
    __syncthreads();
    for (int o = SCAN_TPB / 2; o > 0; o >>= 1) {
        if (t < o) sdata[t] += sdata[t + o];
        __syncthreads();
    }
    if (t == 0) bsum[b] = sdata[0];
}

__global__ __launch_bounds__(SCAN_TPB) void scanB_kernel(
    int* __restrict__ bsum, int nb)   // in-place exclusive scan, nb <= 256
{
    __shared__ int sdata[SCAN_TPB];
    int t = threadIdx.x;
    int v = (t < nb) ? bsum[t] : 0;
    sdata[t] = v;
    __syncthreads();
    for (int o = 1; o < SCAN_TPB; o <<= 1) {
        int u = (t >= o) ? sdata[t - o] : 0;
        __syncthreads();
        sdata[t] += u;
        __syncthreads();
    }
    if (t < nb) bsum[t] = sdata[t] - v;   // exclusive
}

__global__ __launch_bounds__(SCAN_TPB) void scanC_kernel(
    const int* __restrict__ cnt, const int* __restrict__ bsum,
    int* __restrict__ off, int n)
{
    __shared__ int sdata[SCAN_TPB];
    int b = blockIdx.x, t = threadIdx.x;
    int i4 = b * SCAN_EPB + t * 4;
    int4 v = make_int4(0, 0, 0, 0);
    if (i4 + 3 < n) {
        v = *(const int4*)(cnt + i4);
    } else {
        if (i4 + 0 < n) v.x = cnt[i4 + 0];
        if (i4 + 1 < n) v.y = cnt[i4 + 1];
        if (i4 + 2 < n) v.z = cnt[i4 + 2];
    }
    int tot = v.x + v.y + v.z + v.w;
    sdata[t] = tot;
    __syncthreads();
    for (int o = 1; o < SCAN_TPB; o <<= 1) {
        int u = (t >= o) ? sdata[t - o] : 0;
        __syncthreads();
        sdata[t] += u;
        __syncthreads();
    }
    int run = bsum[b] + sdata[t] - tot;    // exclusive prefix of this thread's 4
    int4 o4;
    o4.x = run;
    o4.y = run + v.x;
    o4.z = run + v.x + v.y;
    o4.w = run + v.x + v.y + v.z;
    if (i4 + 3 < n) {
        *(int4*)(off + i4) = o4;
    } else {
        if (i4 + 0 < n) off[i4 + 0] = o4.x;
        if (i4 + 1 < n) off[i4 + 1] = o4.y;
        if (i4 + 2 < n) off[i4 + 2] = o4.z;
    }
}

__global__ __launch_bounds__(256) void scatter_kernel(
    const int* __restrict__ dst, const int* __restrict__ src,
    const int* __restrict__ off, const int* __restrict__ hrep,
    const int* __restrict__ rank1, const int* __restrict__ rank2,
    int* __restrict__ list, int E, int N, int nseg)
{
    int t = blockIdx.x * blockDim.x + threadIdx.x;
    if (t >= E) return;
    const int* hp = hrep + (size_t)(blockIdx.x & (NREP - 1)) * nseg;
    int b1 = dst[t];
    int p1 = off[b1] + hp[b1] + rank1[t];
    __builtin_nontemporal_store(t, &list[p1]);
    int b2 = N + src[t];
    int p2 = off[b2] + hp[b2] + rank2[t];
    __builtin_nontemporal_store(t, &list[p2]);
}

// ---------------------------------------------------------------------------
// One 64-lane wave per node; sides processed sequentially by the full wave.
// Half h handles edges at positions == h (mod 2); lane (h,l) accumulates
// vector component l. 2-deep register software pipeline (16 loads/group in
// flight via compiler-counted vmcnt). Mix phase: halves split the v-sum.
// (unchanged from round 2 -- isolates the build-pipeline delta)
// ---------------------------------------------------------------------------

#define ISSUE(G, wv, xv)                                                    \
  { _Pragma("unroll")                                                       \
    for (int k_ = 0; k_ < 4; ++k_) {                                        \
      int e_ = __shfl(idv, (h << 5) + ((G) << 2) + k_, 64);                 \
      const float* xp_ = xe + (size_t)e_ * ROW_F + l;                       \
      wv[k_]      = W[(size_t)e_ * NVEC + l];                               \
      xv[k_*3+0]  = xp_[0];                                                 \
      xv[k_*3+1]  = xp_[32];                                                \
      xv[k_*3+2]  = xp_[64];                                                \
    } }

#define CONSUME(G, wv, xv)                                                  \
  { _Pragma("unroll")                                                       \
    for (int k_ = 0; k_ < 4; ++k_) {                                        \
      int pos_ = i0 + ((G) << 3) + 2*k_ + h;                                \
      float wk_ = (pos_ < c) ? wv[k_] : 0.f;                                \
      a0 += wk_ * xv[k_*3+0];                                               \
      a1 += wk_ * xv[k_*3+1];                                               \
      a2 += wk_ * xv[k_*3+2];                                               \
    } }

__global__ __launch_bounds__(256, 4) void gather_mix_kernel(
    const float* __restrict__ xe,     // [E,3,32]
    const float* __restrict__ W,      // [E,32]
    const float* __restrict__ M1, const float* __restrict__ M2,
    const int* __restrict__ cnt, const int* __restrict__ off,
    const int* __restrict__ list,
    float* __restrict__ out,          // [N,3,32]
    int N)
{
    __shared__ float As[NVEC * NVEC];
    __shared__ float Bs[NVEC * NVEC];
    for (int i = threadIdx.x; i < NVEC * NVEC; i += blockDim.x) {
        float m1 = M1[i], m2 = M2[i];
        As[i] = 0.5f * (m1 + m2);
        Bs[i] = 0.5f * (m2 - m1);
    }
    __syncthreads();

    int wave = threadIdx.x >> 6;                 // 0..3
    int n = blockIdx.x * 4 + wave;
    if (n >= N) return;
    int lane = threadIdx.x & 63;
    int h = lane >> 5;                            // even/odd edge half
    int l = lane & 31;                            // vector component

    float accD0 = 0.f, accD1 = 0.f, accD2 = 0.f;
    float accS0 = 0.f, accS1 = 0.f, accS2 = 0.f;

    #pragma unroll
    for (int side = 0; side < 2; ++side) {
        int seg  = side ? (N + n) : n;
        int c    = __builtin_amdgcn_readfirstlane(cnt[seg]);
        int base = __builtin_amdgcn_readfirstlane(off[seg]);

        float a0 = 0.f, a1 = 0.f, a2 = 0.f;

        for (int i0 = 0; i0 < c; i0 += 64) {
            int rem = c - i0; if (rem > 64) rem = 64;
            int p2  = 2 * l + h;
            int idv = list[base + i0 + (p2 < rem ? p2 : rem - 1)];
            int ng  = (rem + 7) >> 3;            // groups of 8 edges

            float wA[4], xA[12], wB[4], xB[12];
            ISSUE(0, wA, xA);
            int g = 0;
            while (true) {
                if (g + 1 < ng) ISSUE(g + 1, wB, xB);
                CONSUME(g, wA, xA);
                ++g; if (g >= ng) break;
                if (g + 1 < ng) ISSUE(g + 1, wA, xA);
                CONSUME(g, wB, xB);
                ++g; if (g >= ng) break;
            }
        }

        if (side == 0) { accD0 = a0; accD1 = a1; accD2 = a2; }
        else           { accS0 = a0; accS1 = a1; accS2 = a2; }
    }

    // combine even/odd-edge partials
    accD0 += __shfl_xor(accD0, 32, 64);
    accD1 += __shfl_xor(accD1, 32, 64);
    accD2 += __shfl_xor(accD2, 32, 64);
    accS0 += __shfl_xor(accS0, 32, 64);
    accS1 += __shfl_xor(accS1, 32, 64);
    accS2 += __shfl_xor(accS2, 32, 64);

    // mix: out[m][l] = sum_v accD[m][v]*A[v][l] + accS[m][v]*B[v][l]
    float o0 = 0.f, o1 = 0.f, o2 = 0.f;
    int vbase = h << 4;
    #pragma unroll
    for (int j = 0; j < 16; ++j) {
        int v = vbase + j;
        float Av = As[v * NVEC + l];
        float Bv = Bs[v * NVEC + l];
        float d0 = __shfl(accD0, v, 64), s0 = __shfl(accS0, v, 64);
        float d1 = __shfl(accD1, v, 64), s1 = __shfl(accS1, v, 64);
        float d2 = __shfl(accD2, v, 64), s2 = __shfl(accS2, v, 64);
        o0 += d0 * Av + s0 * Bv;
        o1 += d1 * Av + s1 * Bv;
        o2 += d2 * Av + s2 * Bv;
    }
    o0 += __shfl_xor(o0, 32, 64);
    o1 += __shfl_xor(o1, 32, 64);
    o2 += __shfl_xor(o2, 32, 64);

    float* orow = out + (size_t)n * ROW_F;
    orow[lane] = h ? o1 : o0;        // lanes 0-31 -> row0, 32-63 -> row1
    if (!h) orow[64 + l] = o2;       // half 0 writes row2
}

extern "C" void kernel_launch(void* const* d_in, const int* in_sizes, int n_in,
                              void* d_out, int out_size, void* d_ws, size_t ws_size,
                              hipStream_t stream)
{
    const float* xe  = (const float*)d_in[0];
    const float* W   = (const float*)d_in[1];
    const float* M1  = (const float*)d_in[2];
    const float* M2  = (const float*)d_in[3];
    const int* xsrc  = (const int*)d_in[4];
    const int* xdst  = (const int*)d_in[5];

    const int E = in_sizes[4];
    const int N = out_size / ROW_F;
    const int nseg = 2 * N;

    int* wsi   = (int*)d_ws;
    int* hrep  = wsi;                                   // NREP * 2N
    int* tot   = wsi + (size_t)NREP * nseg;             // 2N
    int* off   = tot + nseg;                            // 2N
    int* rank1 = off + nseg;                            // E
    int* rank2 = rank1 + E;                             // E
    int* list  = rank2 + E;                             // 2E
    int* bsum  = list + 2 * E;                          // 256
    // ws need: (10N + 4E + 256)*4 ~= 17 MB

    hipMemsetAsync(hrep, 0, (size_t)NREP * nseg * sizeof(int), stream);

    const int eblocks = (E + 255) / 256;
    hist_kernel<<<eblocks, 256, 0, stream>>>(xdst, xsrc, hrep, rank1, rank2, E, N, nseg);

    const int rblocks = (nseg / 4 + 255) / 256;
    reduce_kernel<<<rblocks, 256, 0, stream>>>(hrep, tot, nseg);

    const int nscan = (nseg + SCAN_EPB - 1) / SCAN_EPB;   // <= 256 blocks
    scanA_kernel<<<nscan, SCAN_TPB, 0, stream>>>(tot, bsum, nseg);
    scanB_kernel<<<1, SCAN_TPB, 0, stream>>>(bsum, nscan);
    scanC_kernel<<<nscan, SCAN_TPB, 0, stream>>>(tot, bsum, off, nseg);

    scatter_kernel<<<eblocks, 256, 0, stream>>>(
        xdst, xsrc, off, hrep, rank1, rank2, list, E, N, nseg);

    const int nblocks = (N + 3) / 4;              // 4 nodes (waves) per block
    gather_mix_kernel<<<nblocks, 256, 0, stream>>>(
        xe, W, M1, M2, tot, off, list, (float*)d_out, N);
}